// Round 2
// baseline (368.614 us; speedup 1.0000x reference)
//
#include <hip/hip_runtime.h>
#include <math.h>
#include <limits.h>

#define NEG_INF -1e9f

// Zero the last-block ticket counter (ws is re-poisoned every iteration).
__global__ void k_init(int* __restrict__ counter) { *counter = 0; }

// Fused single-pass kernel: one WAVE per path.
//  - gathers only the edge rows that valid paths actually reference
//    (~57% of edges when ~50% of paths are masked) instead of streaming
//    all 100K rows like the old K1; duplicate rows hit L3.
//  - logit_p = dot( (sum_j emb[e_j]) / len, W ) + b   (wave float4 + shfl)
//  - per-block softmax partials (max, first-idx argmax, sum exp(l - bm))
//  - last block (device-scope ticket) combines partials, computes p,
//    logprob = -log(S), and materializes z[p].
__global__ __launch_bounds__(256) void k_all(
    const float* __restrict__ emb, const int* __restrict__ paths,
    const int* __restrict__ path_lens, const int* __restrict__ path_mask,
    const float* __restrict__ W, const float* __restrict__ b,
    float* __restrict__ pmax, int* __restrict__ pidx, float* __restrict__ psum,
    int* __restrict__ counter, float* __restrict__ out,
    int n_paths, int max_len)
{
    __shared__ float wvv[4];  __shared__ int wvi[4];  __shared__ int wva[4];
    __shared__ float rv[4];   __shared__ int ri[4];   __shared__ float rs[4];
    __shared__ float s_M, s_S;
    __shared__ int   s_P, s_last;

    const int tid = threadIdx.x, lane = tid & 63, wv = tid >> 6;
    const int p = blockIdx.x * 4 + wv;

    // ---- per-path logit (one wave per path; masked paths skip all gathers) ----
    float v = NEG_INF; int vi = INT_MAX; int act = 0;
    if (p < n_paths) {
        vi = p; act = 1;
        if (path_mask[p] != 0) {
            const int len = path_lens[p] + 1;               // 1..max_len
            const float4* emb4 = (const float4*)emb;
            float4 acc = make_float4(0.f, 0.f, 0.f, 0.f);
            if (max_len == 16) {
                const int4* pp4 = (const int4*)(paths + (size_t)p * 16);
                int4 a0 = pp4[0], a1 = pp4[1], a2 = pp4[2], a3 = pp4[3];
                int idx[16] = { a0.x, a0.y, a0.z, a0.w, a1.x, a1.y, a1.z, a1.w,
                                a2.x, a2.y, a2.z, a2.w, a3.x, a3.y, a3.z, a3.w };
#pragma unroll
                for (int j = 0; j < 16; ++j) {
                    // unconditional (clamped) load -> 16 independent loads, full ILP;
                    // j >= len re-reads row idx[0] (L1 hit), contribution zeroed.
                    int e = (j < len) ? idx[j] : idx[0];
                    float4 t = emb4[(size_t)e * 64 + lane];
                    acc.x += (j < len) ? t.x : 0.f;
                    acc.y += (j < len) ? t.y : 0.f;
                    acc.z += (j < len) ? t.z : 0.f;
                    acc.w += (j < len) ? t.w : 0.f;
                }
            } else {
                const int* pp = paths + (size_t)p * max_len;
                for (int j = 0; j < len; ++j) {
                    float4 t = emb4[(size_t)pp[j] * 64 + lane];
                    acc.x += t.x; acc.y += t.y; acc.z += t.z; acc.w += t.w;
                }
            }
            const float fl = (float)len;
            const float4 w4 = ((const float4*)W)[lane];
            float d = (acc.x / fl) * w4.x + (acc.y / fl) * w4.y
                    + (acc.z / fl) * w4.z + (acc.w / fl) * w4.w;
#pragma unroll
            for (int off = 32; off; off >>= 1) d += __shfl_down(d, off, 64);
            v = d + b[0];                                    // lane 0 holds it
        }
    }
    if (lane == 0) { wvv[wv] = v; wvi[wv] = vi; wva[wv] = act; }
    __syncthreads();

    // ---- block partials over the 4 wave-logits; publish + ticket ----
    if (tid == 0) {
        float bm = -INFINITY; int bi = INT_MAX;
        for (int w = 0; w < 4; ++w)
            if (wva[w] && (wvv[w] > bm || (wvv[w] == bm && wvi[w] < bi)))
                { bm = wvv[w]; bi = wvi[w]; }
        float bs = 0.f;
        if (bi != INT_MAX) {
            for (int w = 0; w < 4; ++w)
                if (wva[w]) bs += expf(wvv[w] - bm);
        } else { bm = -INFINITY; }                           // no valid path in block
        pmax[blockIdx.x] = bm;
        pidx[blockIdx.x] = bi;
        psum[blockIdx.x] = bs;
        __threadfence();                                     // release partials
        int tk = atomicAdd(counter, 1);                      // device-scope RMW
        s_last = (tk == (int)gridDim.x - 1) ? 1 : 0;
    }
    __syncthreads();
    if (!s_last) return;
    __threadfence();                                         // acquire partials

    // ---- combine: global max + first-index argmax over nb partials ----
    const int nb = gridDim.x;
    float mv = -INFINITY; int mi = INT_MAX;
    for (int i = tid; i < nb; i += 256) {
        float t = pmax[i]; int ti = pidx[i];
        if (t > mv || (t == mv && ti < mi)) { mv = t; mi = ti; }
    }
#pragma unroll
    for (int off = 32; off; off >>= 1) {
        float ov = __shfl_down(mv, off, 64);
        int   oi = __shfl_down(mi, off, 64);
        if (ov > mv || (ov == mv && oi < mi)) { mv = ov; mi = oi; }
    }
    if (lane == 0) { rv[wv] = mv; ri[wv] = mi; }
    __syncthreads();
    if (tid == 0) {
        float M = rv[0]; int P = ri[0];
        for (int w = 1; w < 4; ++w)
            if (rv[w] > M || (rv[w] == M && ri[w] < P)) { M = rv[w]; P = ri[w]; }
        s_M = M; s_P = P;
    }
    __syncthreads();
    const float M = s_M; const int P = s_P;

    // ---- S = sum_b psum[b] * exp(pmax[b] - M) ----
    // empty blocks: psum=0, exp(-inf - M)=0 -> 0. all-masked: exact -log(n).
    float sp = 0.f;
    for (int i = tid; i < nb; i += 256)
        sp += psum[i] * expf(pmax[i] - M);
#pragma unroll
    for (int off = 32; off; off >>= 1) sp += __shfl_down(sp, off, 64);
    if (lane == 0) rs[wv] = sp;
    __syncthreads();
    if (tid == 0) s_S = rs[0] + rs[1] + rs[2] + rs[3];
    __syncthreads();

    // ---- z[P]: 256 threads, one per hidden dim, in-order sum over edges ----
    const int lenP = path_lens[P] + 1;
    const int* pp = paths + (size_t)P * max_len;
    float acc = 0.f;
    for (int j = 0; j < lenP; ++j)
        acc += emb[(size_t)pp[j] * 256 + tid];
    out[2 + tid] = acc / (float)lenP;
    if (tid == 0) { out[0] = (float)P; out[1] = -logf(s_S); } // l_P == M exactly
}

extern "C" void kernel_launch(void* const* d_in, const int* in_sizes, int n_in,
                              void* d_out, int out_size, void* d_ws, size_t ws_size,
                              hipStream_t stream) {
    const float* emb       = (const float*)d_in[0];   // [n_edges, 256]
    const int*   paths     = (const int*)  d_in[1];   // [n_paths, max_len]
    const int*   path_lens = (const int*)  d_in[2];   // [n_paths]
    const int*   path_mask = (const int*)  d_in[3];   // [n_paths]
    const float* W         = (const float*)d_in[4];   // [256]
    const float* b         = (const float*)d_in[5];   // [1]

    int hidden  = in_sizes[4];                 // 256
    int n_paths = in_sizes[2];                 // 20000
    int max_len = in_sizes[1] / n_paths;       // 16
    (void)hidden;

    int blocks = (n_paths + 3) / 4;            // 4 paths (waves) per block

    // workspace layout
    float* pmax    = (float*)d_ws;             // [blocks]
    float* psum    = pmax + blocks;            // [blocks]
    int*   pidx    = (int*)(psum + blocks);    // [blocks]
    int*   counter = pidx + blocks;            // [1]

    k_init<<<1, 1, 0, stream>>>(counter);
    k_all<<<blocks, 256, 0, stream>>>(emb, paths, path_lens, path_mask, W, b,
                                      pmax, pidx, psum, counter,
                                      (float*)d_out, n_paths, max_len);
}

// Round 3
// 176.147 us; speedup vs baseline: 2.0926x; 2.0926x over previous
//
#include <hip/hip_runtime.h>
#include <math.h>
#include <limits.h>

#define NEG_INF -1e9f

// ==================== fast path (max_len == 16, hidden == 256) ====================

// P1: mark edges referenced by valid paths. one thread per (path, slot).
// Coalesced path reads; scattered byte writes (same-value races benign).
__global__ __launch_bounds__(256) void k_scatter16(
    const int* __restrict__ paths, const int* __restrict__ path_lens,
    const int* __restrict__ path_mask, unsigned char* __restrict__ flags,
    int n_paths)
{
    int t = blockIdx.x * 256 + (int)threadIdx.x;
    if (t >= n_paths * 16) return;
    int p = t >> 4;
    if (path_mask[p] == 0) return;
    if ((t & 15) > path_lens[p]) return;       // slot < len = lens+1
    flags[paths[t]] = 1;
}

// P2: s[e] = dot(emb[e], W) for LIVE edges only. One wave per 256-float row,
// grid-stride for ILP across rows. Dead rows (~43%) are never fetched.
__global__ __launch_bounds__(256) void k_dot_flag(
    const float* __restrict__ emb, const float* __restrict__ W,
    const unsigned char* __restrict__ flags, float* __restrict__ s,
    int n_edges, int n_waves)
{
    int wave = (blockIdx.x * 256 + (int)threadIdx.x) >> 6;
    int lane = threadIdx.x & 63;
    const float4 w4 = ((const float4*)W)[lane];
    for (int e = wave; e < n_edges; e += n_waves) {
        if (!flags[e]) continue;
        float4 r = ((const float4*)emb)[(size_t)e * 64 + lane];
        float d = r.x * w4.x + r.y * w4.y + r.z * w4.z + r.w * w4.w;
#pragma unroll
        for (int off = 32; off; off >>= 1) d += __shfl_down(d, off, 64);
        if (lane == 0) s[e] = d;
    }
}

// P3: logits + softmax partials + last-block finalize.
// One thread per (path, slot): 320K threads / 313 blocks of 1024 -> gathers
// spread across all CUs (vs 79 blocks before), path loads fully coalesced.
__global__ __launch_bounds__(1024) void k_fused16(
    const float* __restrict__ s, const int* __restrict__ paths,
    const int* __restrict__ path_lens, const int* __restrict__ path_mask,
    const float* __restrict__ b, const float* __restrict__ emb,
    float* __restrict__ pmax, int* __restrict__ pidx, float* __restrict__ psum,
    int* __restrict__ counter, float* __restrict__ out,
    int n_paths, int max_len)
{
    __shared__ float l_log[64];
    __shared__ int   l_idx[64];
    __shared__ float rv[16]; __shared__ int ri[16]; __shared__ float rs[16];
    __shared__ float s_M, s_S; __shared__ int s_P, s_last;

    const int tid = threadIdx.x, lane = tid & 63, wv = tid >> 6;
    const int t = blockIdx.x * 1024 + tid;
    const int p = t >> 4, slot = t & 15;

    // ---- per-slot gather + 16-lane segmented sum ----
    float val = 0.f; int mask = 0, len = 1; const int inb = (p < n_paths);
    if (inb) {
        mask = path_mask[p];                    // 16-lane broadcast
        len  = path_lens[p] + 1;                // 1..16
        if (mask && slot < len) val = s[paths[t]];   // exec-masked gather
    }
#pragma unroll
    for (int m = 1; m <= 8; m <<= 1) val += __shfl_xor(val, m, 16);
    if (slot == 0) {
        l_log[tid >> 4] = inb ? (mask ? val / (float)len + b[0] : NEG_INF)
                              : -INFINITY;
        l_idx[tid >> 4] = inb ? p : INT_MAX;
    }
    __syncthreads();

    // ---- wave 0 reduces the block's 64 logits -> block partial + ticket ----
    if (wv == 0) {
        float v = l_log[lane]; int vi = l_idx[lane];
        float bv = v; int bi = vi;
#pragma unroll
        for (int off = 32; off; off >>= 1) {
            float ov = __shfl_down(bv, off, 64);
            int   oi = __shfl_down(bi, off, 64);
            if (ov > bv || (ov == bv && oi < bi)) { bv = ov; bi = oi; }
        }
        float bm = __shfl(bv, 0, 64);           // broadcast block max
        float se = expf(v - bm);                // exp(-inf - bm) = 0 for OOB rows
#pragma unroll
        for (int off = 32; off; off >>= 1) se += __shfl_down(se, off, 64);
        if (lane == 0) {
            pmax[blockIdx.x] = bv;
            pidx[blockIdx.x] = bi;
            psum[blockIdx.x] = (bi == INT_MAX) ? 0.f : se;  // all-OOB guard
            __threadfence();                    // release partials
            int tk = atomicAdd(counter, 1);     // device-scope ticket
            s_last = (tk == (int)gridDim.x - 1) ? 1 : 0;
        }
    }
    __syncthreads();
    if (!s_last) return;
    __threadfence();                            // acquire all partials

    // ---- combine: global max + first-index argmax over nb partials ----
    const int nb = gridDim.x;
    float mv = -INFINITY; int mi = INT_MAX;
    for (int i = tid; i < nb; i += 1024) {
        float tv = pmax[i]; int ti = pidx[i];
        if (tv > mv || (tv == mv && ti < mi)) { mv = tv; mi = ti; }
    }
#pragma unroll
    for (int off = 32; off; off >>= 1) {
        float ov = __shfl_down(mv, off, 64);
        int   oi = __shfl_down(mi, off, 64);
        if (ov > mv || (ov == mv && oi < mi)) { mv = ov; mi = oi; }
    }
    if (lane == 0) { rv[wv] = mv; ri[wv] = mi; }
    __syncthreads();
    if (tid == 0) {
        float M = rv[0]; int P = ri[0];
        for (int w = 1; w < 16; ++w)
            if (rv[w] > M || (rv[w] == M && ri[w] < P)) { M = rv[w]; P = ri[w]; }
        s_M = M; s_P = P;
    }
    __syncthreads();
    const float M = s_M; const int P = s_P;

    // ---- S = sum_b psum[b] * exp(pmax[b] - M);  empty blocks contribute 0 ----
    float sp = 0.f;
    for (int i = tid; i < nb; i += 1024)
        sp += psum[i] * expf(pmax[i] - M);
#pragma unroll
    for (int off = 32; off; off >>= 1) sp += __shfl_down(sp, off, 64);
    if (lane == 0) rs[wv] = sp;
    __syncthreads();
    if (tid == 0) {
        float tot = 0.f;
        for (int w = 0; w < 16; ++w) tot += rs[w];
        s_S = tot;
    }
    __syncthreads();

    // ---- z[P]: 256 threads, one per hidden dim, in-order edge sum ----
    const int lenP = path_lens[P] + 1;
    const int* pp = paths + (size_t)P * max_len;
    if (tid < 256) {
        float acc = 0.f;
        for (int j = 0; j < lenP; ++j)
            acc += emb[(size_t)pp[j] * 256 + tid];
        out[2 + tid] = acc / (float)lenP;
    }
    if (tid == 0) { out[0] = (float)P; out[1] = -logf(s_S); }  // l_P == M exactly
}

// ==================== generic fallback (round-1 structure) ====================

__global__ __launch_bounds__(256) void k_edge_dot(
    const float* __restrict__ emb, const float* __restrict__ W,
    float* __restrict__ s, int* __restrict__ counter, int n_edges)
{
    if (blockIdx.x == 0 && threadIdx.x == 0) *counter = 0;
    int wave = (blockIdx.x * (int)blockDim.x + (int)threadIdx.x) >> 6;
    int lane = threadIdx.x & 63;
    if (wave >= n_edges) return;
    const float4 e = ((const float4*)emb)[(size_t)wave * 64 + lane];
    const float4 w = ((const float4*)W)[lane];
    float d = e.x * w.x + e.y * w.y + e.z * w.z + e.w * w.w;
#pragma unroll
    for (int off = 32; off; off >>= 1) d += __shfl_down(d, off, 64);
    if (lane == 0) s[wave] = d;
}

__global__ __launch_bounds__(256) void k_fused_gen(
    const float* __restrict__ s, const int* __restrict__ paths,
    const int* __restrict__ path_lens, const int* __restrict__ path_mask,
    const float* __restrict__ b, const float* __restrict__ emb,
    float* __restrict__ pmax, int* __restrict__ pidx, float* __restrict__ psum,
    int* __restrict__ counter, float* __restrict__ out,
    int n_paths, int max_len)
{
    __shared__ float rv[4]; __shared__ int ri[4]; __shared__ float rs[4];
    __shared__ float s_M, s_S; __shared__ int s_P, s_last;

    const int tid = threadIdx.x, lane = tid & 63, wv = tid >> 6;
    const int p = blockIdx.x * 256 + tid;

    float v = -INFINITY; int vi = INT_MAX;
    if (p < n_paths) {
        vi = p;
        if (path_mask[p] == 0) v = NEG_INF;
        else {
            int len = path_lens[p] + 1;
            const int* pp = paths + (size_t)p * max_len;
            float acc = 0.f;
            for (int j = 0; j < len; ++j) acc += s[pp[j]];
            v = acc / (float)len + b[0];
        }
    }
    float bv = v; int bi = vi;
#pragma unroll
    for (int off = 32; off; off >>= 1) {
        float ov = __shfl_down(bv, off, 64);
        int   oi = __shfl_down(bi, off, 64);
        if (ov > bv || (ov == bv && oi < bi)) { bv = ov; bi = oi; }
    }
    if (lane == 0) { rv[wv] = bv; ri[wv] = bi; }
    __syncthreads();
    if (tid == 0) {
        float mvv = rv[0]; int mii = ri[0];
        for (int w = 1; w < 4; ++w)
            if (rv[w] > mvv || (rv[w] == mvv && ri[w] < mii)) { mvv = rv[w]; mii = ri[w]; }
        s_M = mvv; s_P = mii;
    }
    __syncthreads();
    const float bm = s_M;
    float se = expf(v - bm);
#pragma unroll
    for (int off = 32; off; off >>= 1) se += __shfl_down(se, off, 64);
    if (lane == 0) rs[wv] = se;
    __syncthreads();
    if (tid == 0) {
        pmax[blockIdx.x] = bm;
        pidx[blockIdx.x] = s_P;
        psum[blockIdx.x] = rs[0] + rs[1] + rs[2] + rs[3];
        __threadfence();
        int tk = atomicAdd(counter, 1);
        s_last = (tk == (int)gridDim.x - 1) ? 1 : 0;
    }
    __syncthreads();
    if (!s_last) return;
    __threadfence();

    const int nb = gridDim.x;
    float mv = -INFINITY; int mi = INT_MAX;
    for (int i = tid; i < nb; i += 256) {
        float tv = pmax[i]; int ti = pidx[i];
        if (tv > mv || (tv == mv && ti < mi)) { mv = tv; mi = ti; }
    }
#pragma unroll
    for (int off = 32; off; off >>= 1) {
        float ov = __shfl_down(mv, off, 64);
        int   oi = __shfl_down(mi, off, 64);
        if (ov > mv || (ov == mv && oi < mi)) { mv = ov; mi = oi; }
    }
    if (lane == 0) { rv[wv] = mv; ri[wv] = mi; }
    __syncthreads();
    if (tid == 0) {
        float M = rv[0]; int P = ri[0];
        for (int w = 1; w < 4; ++w)
            if (rv[w] > M || (rv[w] == M && ri[w] < P)) { M = rv[w]; P = ri[w]; }
        s_M = M; s_P = P;
    }
    __syncthreads();
    const float M = s_M; const int P = s_P;
    float sp = 0.f;
    for (int i = tid; i < nb; i += 256)
        sp += psum[i] * expf(pmax[i] - M);
#pragma unroll
    for (int off = 32; off; off >>= 1) sp += __shfl_down(sp, off, 64);
    if (lane == 0) rs[wv] = sp;
    __syncthreads();
    if (tid == 0) s_S = rs[0] + rs[1] + rs[2] + rs[3];
    __syncthreads();

    const int lenP = path_lens[P] + 1;
    const int* pp = paths + (size_t)P * max_len;
    if (tid < 256) {
        float acc = 0.f;
        for (int j = 0; j < lenP; ++j)
            acc += emb[(size_t)pp[j] * 256 + tid];
        out[2 + tid] = acc / (float)lenP;
    }
    if (tid == 0) { out[0] = (float)P; out[1] = -logf(s_S); }
}

// ==================== launcher ====================

extern "C" void kernel_launch(void* const* d_in, const int* in_sizes, int n_in,
                              void* d_out, int out_size, void* d_ws, size_t ws_size,
                              hipStream_t stream) {
    const float* emb       = (const float*)d_in[0];   // [n_edges, 256]
    const int*   paths     = (const int*)  d_in[1];   // [n_paths, max_len]
    const int*   path_lens = (const int*)  d_in[2];   // [n_paths]
    const int*   path_mask = (const int*)  d_in[3];   // [n_paths]
    const float* W         = (const float*)d_in[4];   // [256]
    const float* b         = (const float*)d_in[5];   // [1]

    int hidden  = in_sizes[4];                 // 256
    int n_edges = in_sizes[0] / hidden;        // 100000
    int n_paths = in_sizes[2];                 // 20000
    int max_len = in_sizes[1] / n_paths;       // 16

    if (max_len == 16 && hidden == 256) {
        size_t flags_pad = ((size_t)n_edges + 255) & ~(size_t)255;
        unsigned char* flags = (unsigned char*)d_ws;            // [n_edges]
        int*   counter = (int*)(flags + flags_pad);             // [1]
        float* s       = (float*)(flags + flags_pad + 256);     // [n_edges]
        int nb3 = (n_paths * 16 + 1023) / 1024;                 // 313
        float* pmax = s + n_edges;                              // [nb3]
        float* psum = pmax + nb3;                               // [nb3]
        int*   pidx = (int*)(psum + nb3);                       // [nb3]

        // zero flags + ticket counter (ws is re-poisoned every iteration)
        hipMemsetAsync(d_ws, 0, flags_pad + sizeof(int), stream);

        int blocksS = (n_paths * 16 + 255) / 256;               // 1250
        k_scatter16<<<blocksS, 256, 0, stream>>>(paths, path_lens, path_mask,
                                                 flags, n_paths);

        int blocksD = 4096;                                     // 16384 waves
        k_dot_flag<<<blocksD, 256, 0, stream>>>(emb, W, flags, s,
                                                n_edges, blocksD * 4);

        k_fused16<<<nb3, 1024, 0, stream>>>(s, paths, path_lens, path_mask,
                                            b, emb, pmax, pidx, psum, counter,
                                            (float*)d_out, n_paths, max_len);
    } else {
        // generic fallback: full stream + one-thread-per-path (round-1 structure)
        float* s = (float*)d_ws;
        int blocks2 = (n_paths + 255) / 256;
        float* pmax    = s + n_edges;
        float* psum    = pmax + blocks2;
        int*   pidx    = (int*)(psum + blocks2);
        int*   counter = pidx + blocks2;

        int blocks1 = (n_edges * 64 + 255) / 256;
        k_edge_dot<<<blocks1, 256, 0, stream>>>(emb, W, s, counter, n_edges);
        k_fused_gen<<<blocks2, 256, 0, stream>>>(s, paths, path_lens, path_mask,
                                                 b, emb, pmax, pidx, psum, counter,
                                                 (float*)d_out, n_paths, max_len);
    }
}